// Round 1
// baseline (382.428 us; speedup 1.0000x reference)
//
#include <hip/hip_runtime.h>
#include <hip/hip_bf16.h>
#include <math.h>

// Problem constants
#define BB 16
#define QQ 100
#define CD 256          // query/channel dim
#define OD 256          // hidden dim
#define NH 8
#define HD 32           // head dim
#define HWN 4096        // H*W
#define NORM_FACT 0.17677669529663687f   // 32^-0.5
#define NT 16           // hw tiles in scores kernel (4096/256)

// ---------------- K0: transpose Wq, Wk (256x256) -> coalesced access later ----
__global__ void k_transpose(const float* __restrict__ Wq, const float* __restrict__ Wk,
                            float* __restrict__ WqT, float* __restrict__ WkT) {
    int c = blockIdx.x & 255;
    int m = blockIdx.x >> 8;
    int h = threadIdx.x;
    const float* W = m ? Wk : Wq;
    float*      WT = m ? WkT : WqT;
    WT[c * 256 + h] = W[h * 256 + c];
}

// ---------------- K1: qp[b,q,h] = (q . Wq^T + bq) * NORM ----------------------
// block = (b, 4 queries), 256 threads (one per h)
__global__ __launch_bounds__(256) void k_qproj(const float* __restrict__ q,
                                               const float* __restrict__ WqT,
                                               const float* __restrict__ bq,
                                               float* __restrict__ qp) {
    int blk = blockIdx.x;
    int b = blk / 25, q0 = (blk % 25) * 4;
    int h = threadIdx.x;
    __shared__ float qsh[4][256];
    int base = (b * QQ + q0) * 256;
#pragma unroll
    for (int i = 0; i < 4; ++i) qsh[i][h] = q[base + i * 256 + h];
    __syncthreads();
    float bias = bq[h];
    float a0 = bias, a1 = bias, a2 = bias, a3 = bias;
    for (int c = 0; c < 256; ++c) {
        float wv = WqT[c * 256 + h];         // coalesced, L2-resident
        a0 = fmaf(qsh[0][c], wv, a0);
        a1 = fmaf(qsh[1][c], wv, a1);
        a2 = fmaf(qsh[2][c], wv, a2);
        a3 = fmaf(qsh[3][c], wv, a3);
    }
    qp[base + 0 * 256 + h] = a0 * NORM_FACT;
    qp[base + 1 * 256 + h] = a1 * NORM_FACT;
    qp[base + 2 * 256 + h] = a2 * NORM_FACT;
    qp[base + 3 * 256 + h] = a3 * NORM_FACT;
}

// ---------------- K2: kp[b,o,hw] = Wk . k + bk  (per-batch GEMM 256x256x4096) -
// tile: 128 o x 128 hw, 256 threads, 8x8 micro-tile per thread
__global__ __launch_bounds__(256) void k_kproj(const float* __restrict__ k,
                                               const float* __restrict__ WkT,
                                               const float* __restrict__ bk,
                                               float* __restrict__ kp) {
    int hwb = blockIdx.x * 128;
    int ob  = blockIdx.y * 128;
    int b   = blockIdx.z;
    int t = threadIdx.x;
    int to = t >> 4, thw = t & 15;
    int o0 = to * 8, h0 = thw * 8;
    __shared__ float wsh[8][128];
    __shared__ float ksh[8][128];
    float acc[8][8] = {};
    const float* kb = k + (size_t)b * 256 * HWN;
    for (int c0 = 0; c0 < 256; c0 += 8) {
#pragma unroll
        for (int i = 0; i < 4; ++i) {
            int idx = t + i * 256;
            int ci = idx >> 7, col = idx & 127;
            wsh[ci][col] = WkT[(c0 + ci) * 256 + ob + col];
            ksh[ci][col] = kb[(size_t)(c0 + ci) * HWN + hwb + col];
        }
        __syncthreads();
#pragma unroll
        for (int ci = 0; ci < 8; ++ci) {
            float wv[8], kv[8];
#pragma unroll
            for (int i = 0; i < 8; ++i) wv[i] = wsh[ci][o0 + i];
#pragma unroll
            for (int j = 0; j < 8; ++j) kv[j] = ksh[ci][h0 + j];
#pragma unroll
            for (int i = 0; i < 8; ++i)
#pragma unroll
                for (int j = 0; j < 8; ++j) acc[i][j] = fmaf(wv[i], kv[j], acc[i][j]);
        }
        __syncthreads();
    }
#pragma unroll
    for (int i = 0; i < 8; ++i) {
        float bias = bk[ob + o0 + i];
        float* dst = kp + ((size_t)b * 256 + ob + o0 + i) * HWN + hwb + h0;
#pragma unroll
        for (int j = 0; j < 8; ++j) dst[j] = acc[i][j] + bias;
    }
}

// ---------------- K3: scores -> exp -> out (unnormalized) + per-tile sums -----
// block = (hw tile of 256, q tile of 50, b); thread owns one hw position
__global__ __launch_bounds__(256) void k_scores(const float* __restrict__ qp,
                                                const float* __restrict__ kp,
                                                const int* __restrict__ mask,
                                                float* __restrict__ out,
                                                float* __restrict__ partial) {
    int hwt = blockIdx.x;   // 0..15
    int qt  = blockIdx.y;   // 0..1
    int b   = blockIdx.z;   // 0..15
    int t = threadIdx.x;
    int hw = hwt * 256 + t;
    __shared__ float ssum[50 * 256];   // 50 KB: per-(q, thread) running sums
#pragma unroll 1
    for (int qq = 0; qq < 50; ++qq) ssum[qq * 256 + t] = 0.0f;   // each thread owns its column
    int mv = mask[b * HWN + hw];
    const int qbase = b * QQ + qt * 50;
#pragma unroll 1
    for (int n = 0; n < NH; ++n) {
        float kv[32];
        const float* kpp = kp + ((size_t)(b * 256 + n * 32)) * HWN + hw;
#pragma unroll
        for (int c = 0; c < 32; ++c) kv[c] = kpp[(size_t)c * HWN];
        const float* qrow = qp + (size_t)qbase * 256 + n * 32;   // block-uniform -> s_load
        float* orow = out + (((size_t)qbase * NH) + n) * HWN + hw;
#pragma unroll 1
        for (int qq = 0; qq < 50; ++qq) {
            float s = 0.0f;
#pragma unroll
            for (int c = 0; c < 32; ++c) s = fmaf(qrow[qq * 256 + c], kv[c], s);
            float e = mv ? 0.0f : __expf(s);
            orow[(size_t)qq * (NH * HWN)] = e;
            ssum[qq * 256 + t] += e;
        }
    }
    __syncthreads();
    // tree-reduce the 256 columns per q
    for (int off = 128; off; off >>= 1) {
        if (t < off) {
            for (int qq = 0; qq < 50; ++qq) ssum[qq * 256 + t] += ssum[qq * 256 + t + off];
        }
        __syncthreads();
    }
    if (t < 50) partial[(size_t)(qbase + t) * NT + hwt] = ssum[t * 256];
}

// ---------------- K4: inv_sum[b,q] = 1 / sum over tiles -----------------------
__global__ void k_invsum(const float* __restrict__ partial, float* __restrict__ inv) {
    int i = blockIdx.x * 256 + threadIdx.x;
    if (i < BB * QQ) {
        float s = 0.0f;
#pragma unroll
        for (int j = 0; j < NT; ++j) s += partial[(size_t)i * NT + j];
        inv[i] = 1.0f / s;
    }
}

// ---------------- K5: out *= inv_sum (float4, grid-stride) --------------------
__global__ __launch_bounds__(256) void k_norm(float4* __restrict__ out,
                                              const float* __restrict__ inv) {
    const size_t total = (size_t)BB * QQ * NH * HWN / 4;   // 13,107,200
    size_t stride = (size_t)gridDim.x * 256;
    for (size_t i = (size_t)blockIdx.x * 256 + threadIdx.x; i < total; i += stride) {
        float sc = inv[i >> 13];    // 32768 floats = 8192 float4 per (b,q)
        float4 v = out[i];
        v.x *= sc; v.y *= sc; v.z *= sc; v.w *= sc;
        out[i] = v;
    }
}

extern "C" void kernel_launch(void* const* d_in, const int* in_sizes, int n_in,
                              void* d_out, int out_size, void* d_ws, size_t ws_size,
                              hipStream_t stream) {
    const float* q    = (const float*)d_in[0];
    const float* k    = (const float*)d_in[1];
    const float* Wq   = (const float*)d_in[2];
    const float* bq   = (const float*)d_in[3];
    const float* Wk   = (const float*)d_in[4];
    const float* bk   = (const float*)d_in[5];
    const int*   mask = (const int*)d_in[6];   // bool in ref; assuming int32 on device
    float* out = (float*)d_out;

    float* ws      = (float*)d_ws;
    float* qp      = ws;                       // 409,600
    float* kp      = qp + 409600;              // 16,777,216
    float* WqT     = kp + 16777216;            // 65,536
    float* WkT     = WqT + 65536;              // 65,536
    float* partial = WkT + 65536;              // 25,600
    float* inv     = partial + 25600;          // 1,600
    if (ws_size < (size_t)(409600 + 16777216 + 65536 + 65536 + 25600 + 1600) * 4) return;

    k_transpose<<<dim3(512), dim3(256), 0, stream>>>(Wq, Wk, WqT, WkT);
    k_qproj   <<<dim3(400), dim3(256), 0, stream>>>(q, WqT, bq, qp);
    k_kproj   <<<dim3(32, 2, 16), dim3(256), 0, stream>>>(k, WkT, bk, kp);
    k_scores  <<<dim3(NT, 2, 16), dim3(256), 0, stream>>>(qp, kp, mask, out, partial);
    k_invsum  <<<dim3(7), dim3(256), 0, stream>>>(partial, inv);
    k_norm    <<<dim3(2048), dim3(256), 0, stream>>>((float4*)out, inv);
}

// Round 2
// 329.249 us; speedup vs baseline: 1.1615x; 1.1615x over previous
//
#include <hip/hip_runtime.h>
#include <hip/hip_bf16.h>
#include <math.h>

// Problem constants
#define BB 16
#define QQ 100
#define CD 256          // query/channel dim
#define OD 256          // hidden dim
#define NH 8
#define HD 32           // head dim
#define HWN 4096        // H*W
#define NORM_FACT 0.17677669529663687f   // 32^-0.5
#define NT 16           // hw tiles in scores kernels (4096/256)
#define QT 10           // q rows per scores block

// ---------------- K0: transpose Wq, Wk (256x256) -> coalesced access later ----
__global__ void k_transpose(const float* __restrict__ Wq, const float* __restrict__ Wk,
                            float* __restrict__ WqT, float* __restrict__ WkT) {
    int c = blockIdx.x & 255;
    int m = blockIdx.x >> 8;
    int h = threadIdx.x;
    const float* W = m ? Wk : Wq;
    float*      WT = m ? WkT : WqT;
    WT[c * 256 + h] = W[h * 256 + c];
}

// ---------------- K1: qp[b,q,h] = (q . Wq^T + bq) * NORM ----------------------
__global__ __launch_bounds__(256) void k_qproj(const float* __restrict__ q,
                                               const float* __restrict__ WqT,
                                               const float* __restrict__ bq,
                                               float* __restrict__ qp) {
    int blk = blockIdx.x;
    int b = blk / 25, q0 = (blk % 25) * 4;
    int h = threadIdx.x;
    __shared__ float qsh[4][256];
    int base = (b * QQ + q0) * 256;
#pragma unroll
    for (int i = 0; i < 4; ++i) qsh[i][h] = q[base + i * 256 + h];
    __syncthreads();
    float bias = bq[h];
    float a0 = bias, a1 = bias, a2 = bias, a3 = bias;
    for (int c = 0; c < 256; ++c) {
        float wv = WqT[c * 256 + h];
        a0 = fmaf(qsh[0][c], wv, a0);
        a1 = fmaf(qsh[1][c], wv, a1);
        a2 = fmaf(qsh[2][c], wv, a2);
        a3 = fmaf(qsh[3][c], wv, a3);
    }
    qp[base + 0 * 256 + h] = a0 * NORM_FACT;
    qp[base + 1 * 256 + h] = a1 * NORM_FACT;
    qp[base + 2 * 256 + h] = a2 * NORM_FACT;
    qp[base + 3 * 256 + h] = a3 * NORM_FACT;
}

// ---------------- K2: kp[b,o,hw] = Wk . k + bk  (per-batch GEMM 256x256x4096) -
__global__ __launch_bounds__(256) void k_kproj(const float* __restrict__ k,
                                               const float* __restrict__ WkT,
                                               const float* __restrict__ bk,
                                               float* __restrict__ kp) {
    int hwb = blockIdx.x * 128;
    int ob  = blockIdx.y * 128;
    int b   = blockIdx.z;
    int t = threadIdx.x;
    int to = t >> 4, thw = t & 15;
    int o0 = to * 8, h0 = thw * 8;
    __shared__ float wsh[8][128];
    __shared__ float ksh[8][128];
    float acc[8][8] = {};
    const float* kb = k + (size_t)b * 256 * HWN;
    for (int c0 = 0; c0 < 256; c0 += 8) {
#pragma unroll
        for (int i = 0; i < 4; ++i) {
            int idx = t + i * 256;
            int ci = idx >> 7, col = idx & 127;
            wsh[ci][col] = WkT[(c0 + ci) * 256 + ob + col];
            ksh[ci][col] = kb[(size_t)(c0 + ci) * HWN + hwb + col];
        }
        __syncthreads();
#pragma unroll
        for (int ci = 0; ci < 8; ++ci) {
            float wv[8], kv[8];
#pragma unroll
            for (int i = 0; i < 8; ++i) wv[i] = wsh[ci][o0 + i];
#pragma unroll
            for (int j = 0; j < 8; ++j) kv[j] = ksh[ci][h0 + j];
#pragma unroll
            for (int i = 0; i < 8; ++i)
#pragma unroll
                for (int j = 0; j < 8; ++j) acc[i][j] = fmaf(wv[i], kv[j], acc[i][j]);
        }
        __syncthreads();
    }
#pragma unroll
    for (int i = 0; i < 8; ++i) {
        float bias = bk[ob + o0 + i];
        float* dst = kp + ((size_t)b * 256 + ob + o0 + i) * HWN + hwb + h0;
#pragma unroll
        for (int j = 0; j < 8; ++j) dst[j] = acc[i][j] + bias;
    }
}

// ---------------- K3: sum-pass — scores -> exp -> per-(b,q) tile partial sums -
// grid (16 hw tiles, 10 q tiles, 16 b), 256 threads; thread owns one hw pos
__global__ __launch_bounds__(256) void k_sums(const float* __restrict__ qp,
                                              const float* __restrict__ kp,
                                              const int* __restrict__ mask,
                                              float* __restrict__ partial) {
    int hwt = blockIdx.x, qt = blockIdx.y, b = blockIdx.z;
    int t = threadIdx.x;
    int hw = hwt * 256 + t;
    int mv = mask[b * HWN + hw];
    int qbase = b * QQ + qt * QT;
    const float* qpb = qp + (size_t)qbase * 256;   // block-uniform
    float sums[QT] = {};
#pragma unroll 1
    for (int n = 0; n < NH; ++n) {
        float kv[32];
        const float* kpp = kp + ((size_t)(b * 256 + n * 32)) * HWN + hw;
#pragma unroll
        for (int c = 0; c < 32; ++c) kv[c] = kpp[(size_t)c * HWN];
#pragma unroll
        for (int qq = 0; qq < QT; ++qq) {
            const float* qr = qpb + qq * 256 + n * 32;
            float s0 = 0.f, s1 = 0.f, s2 = 0.f, s3 = 0.f;
#pragma unroll
            for (int c = 0; c < 32; c += 4) {
                s0 = fmaf(qr[c + 0], kv[c + 0], s0);
                s1 = fmaf(qr[c + 1], kv[c + 1], s1);
                s2 = fmaf(qr[c + 2], kv[c + 2], s2);
                s3 = fmaf(qr[c + 3], kv[c + 3], s3);
            }
            float e = __expf((s0 + s1) + (s2 + s3));
            sums[qq] += mv ? 0.0f : e;
        }
    }
    // reduce over 256 threads per q: wave shuffle, then 4 wave-partials in LDS
    __shared__ float red[QT][4];
#pragma unroll
    for (int qq = 0; qq < QT; ++qq) {
        float v = sums[qq];
#pragma unroll
        for (int off = 32; off; off >>= 1) v += __shfl_xor(v, off, 64);
        if ((t & 63) == 0) red[qq][t >> 6] = v;
    }
    __syncthreads();
    if (t < QT) {
        float s = red[t][0] + red[t][1] + red[t][2] + red[t][3];
        partial[(size_t)(qbase + t) * NT + hwt] = s;
    }
}

// ---------------- K4: inv_sum[b,q] = 1 / sum over tiles -----------------------
__global__ void k_invsum(const float* __restrict__ partial, float* __restrict__ inv) {
    int i = blockIdx.x * 256 + threadIdx.x;
    if (i < BB * QQ) {
        float s = 0.0f;
#pragma unroll
        for (int j = 0; j < NT; ++j) s += partial[(size_t)i * NT + j];
        inv[i] = 1.0f / s;
    }
}

// ---------------- K5: write-pass — recompute scores, write normalized ---------
__global__ __launch_bounds__(256) void k_write(const float* __restrict__ qp,
                                               const float* __restrict__ kp,
                                               const int* __restrict__ mask,
                                               const float* __restrict__ inv,
                                               float* __restrict__ out) {
    int hwt = blockIdx.x, qt = blockIdx.y, b = blockIdx.z;
    int t = threadIdx.x;
    int hw = hwt * 256 + t;
    int mv = mask[b * HWN + hw];
    int qbase = b * QQ + qt * QT;
    const float* qpb = qp + (size_t)qbase * 256;
    float invq[QT];
#pragma unroll
    for (int qq = 0; qq < QT; ++qq) invq[qq] = inv[qbase + qq];   // uniform
#pragma unroll 1
    for (int n = 0; n < NH; ++n) {
        float kv[32];
        const float* kpp = kp + ((size_t)(b * 256 + n * 32)) * HWN + hw;
#pragma unroll
        for (int c = 0; c < 32; ++c) kv[c] = kpp[(size_t)c * HWN];
#pragma unroll
        for (int qq = 0; qq < QT; ++qq) {
            const float* qr = qpb + qq * 256 + n * 32;
            float s0 = 0.f, s1 = 0.f, s2 = 0.f, s3 = 0.f;
#pragma unroll
            for (int c = 0; c < 32; c += 4) {
                s0 = fmaf(qr[c + 0], kv[c + 0], s0);
                s1 = fmaf(qr[c + 1], kv[c + 1], s1);
                s2 = fmaf(qr[c + 2], kv[c + 2], s2);
                s3 = fmaf(qr[c + 3], kv[c + 3], s3);
            }
            float e = __expf((s0 + s1) + (s2 + s3)) * invq[qq];
            out[(((size_t)(qbase + qq)) * NH + n) * HWN + hw] = mv ? 0.0f : e;
        }
    }
}

extern "C" void kernel_launch(void* const* d_in, const int* in_sizes, int n_in,
                              void* d_out, int out_size, void* d_ws, size_t ws_size,
                              hipStream_t stream) {
    const float* q    = (const float*)d_in[0];
    const float* k    = (const float*)d_in[1];
    const float* Wq   = (const float*)d_in[2];
    const float* bq   = (const float*)d_in[3];
    const float* Wk   = (const float*)d_in[4];
    const float* bk   = (const float*)d_in[5];
    const int*   mask = (const int*)d_in[6];
    float* out = (float*)d_out;

    float* ws      = (float*)d_ws;
    float* qp      = ws;                       // 409,600
    float* kp      = qp + 409600;              // 16,777,216
    float* WqT     = kp + 16777216;            // 65,536
    float* WkT     = WqT + 65536;              // 65,536
    float* partial = WkT + 65536;              // 25,600
    float* inv     = partial + 25600;          // 1,600
    if (ws_size < (size_t)(409600 + 16777216 + 65536 + 65536 + 25600 + 1600) * 4) return;

    k_transpose<<<dim3(512), dim3(256), 0, stream>>>(Wq, Wk, WqT, WkT);
    k_qproj   <<<dim3(400), dim3(256), 0, stream>>>(q, WqT, bq, qp);
    k_kproj   <<<dim3(32, 2, 16), dim3(256), 0, stream>>>(k, WkT, bk, kp);
    k_sums    <<<dim3(NT, QQ / QT, 16), dim3(256), 0, stream>>>(qp, kp, mask, partial);
    k_invsum  <<<dim3(7), dim3(256), 0, stream>>>(partial, inv);
    k_write   <<<dim3(NT, QQ / QT, 16), dim3(256), 0, stream>>>(qp, kp, mask, inv, out);
}

// Round 3
// 315.520 us; speedup vs baseline: 1.2121x; 1.0435x over previous
//
#include <hip/hip_runtime.h>
#include <hip/hip_bf16.h>
#include <math.h>

// Problem constants
#define BB 16
#define QQ 100
#define NH 8
#define HD 32
#define HWN 4096
#define NORM_FACT 0.17677669529663687f   // 32^-0.5
#define NT 16           // hw tiles in scores kernels (4096/256)
#define QT 10           // q rows per scores block

typedef short bf16x8_t __attribute__((ext_vector_type(8)));
typedef float f32x4_t  __attribute__((ext_vector_type(4)));

__device__ __forceinline__ unsigned short bf16bits(float f) {
    __hip_bfloat16 h = __float2bfloat16(f);           // RNE
    return __builtin_bit_cast(unsigned short, h);
}
__device__ __forceinline__ float bf16tof(unsigned short u) {
    union { unsigned int i; float f; } x; x.i = (unsigned int)u << 16; return x.f;
}

// ---------------- K0: WqT (fp32 transpose) + Wk -> bf16 (no transpose) --------
__global__ void k_prep(const float* __restrict__ Wq, const float* __restrict__ Wk,
                       float* __restrict__ WqT, unsigned short* __restrict__ Wkbf) {
    int idx = blockIdx.x;
    int h = threadIdx.x;
    if (idx < 256) {
        WqT[idx * 256 + h] = Wq[h * 256 + idx];
    } else {
        int r = idx - 256;
        Wkbf[r * 256 + h] = bf16bits(Wk[r * 256 + h]);
    }
}

// ---------------- K1: qp[b,q,h] = (q . Wq^T + bq) * NORM (fp32) ---------------
__global__ __launch_bounds__(256) void k_qproj(const float* __restrict__ q,
                                               const float* __restrict__ WqT,
                                               const float* __restrict__ bq,
                                               float* __restrict__ qp) {
    int blk = blockIdx.x;
    int b = blk / 25, q0 = (blk % 25) * 4;
    int h = threadIdx.x;
    __shared__ float qsh[4][256];
    int base = (b * QQ + q0) * 256;
#pragma unroll
    for (int i = 0; i < 4; ++i) qsh[i][h] = q[base + i * 256 + h];
    __syncthreads();
    float bias = bq[h];
    float a0 = bias, a1 = bias, a2 = bias, a3 = bias;
    for (int c = 0; c < 256; ++c) {
        float wv = WqT[c * 256 + h];
        a0 = fmaf(qsh[0][c], wv, a0);
        a1 = fmaf(qsh[1][c], wv, a1);
        a2 = fmaf(qsh[2][c], wv, a2);
        a3 = fmaf(qsh[3][c], wv, a3);
    }
    qp[base + 0 * 256 + h] = a0 * NORM_FACT;
    qp[base + 1 * 256 + h] = a1 * NORM_FACT;
    qp[base + 2 * 256 + h] = a2 * NORM_FACT;
    qp[base + 3 * 256 + h] = a3 * NORM_FACT;
}

// ---------------- K2a: kT[b][hw][c] bf16 <- k[b][c][hw] fp32 (LDS transpose) --
__global__ __launch_bounds__(256) void k_tconv(const float* __restrict__ k,
                                               unsigned short* __restrict__ kT) {
    int b = blockIdx.z, c0 = blockIdx.y * 64, hw0 = blockIdx.x * 64;
    int t = threadIdx.x;
    __shared__ float lds[64][65];
    const float* src = k + ((size_t)b * 256 + c0) * HWN + hw0;
    int col = t & 63, r0 = t >> 6;
#pragma unroll
    for (int i = 0; i < 16; ++i) {
        int r = i * 4 + r0;
        lds[r][col] = src[(size_t)r * HWN + col];
    }
    __syncthreads();
    int hw = t >> 2, cc = (t & 3) * 16;
    unsigned short* dst = kT + ((size_t)b * HWN + hw0 + hw) * 256 + c0 + cc;
    uint4 v0, v1;
    unsigned int* w0 = (unsigned int*)&v0;
    unsigned int* w1 = (unsigned int*)&v1;
#pragma unroll
    for (int j = 0; j < 4; ++j) {
        w0[j] = (unsigned int)bf16bits(lds[cc + 2*j + 0][hw])
              | ((unsigned int)bf16bits(lds[cc + 2*j + 1][hw]) << 16);
        w1[j] = (unsigned int)bf16bits(lds[cc + 8 + 2*j + 0][hw])
              | ((unsigned int)bf16bits(lds[cc + 8 + 2*j + 1][hw]) << 16);
    }
    *(uint4*)(dst)     = v0;
    *(uint4*)(dst + 8) = v1;
}

// ---------------- K2b: kp[b,o,hw] bf16 = Wk . k + bk via MFMA -----------------
// block = 4 waves; wave computes o=0..255 x 16 hw (16 acc tiles); block covers 64 hw
__global__ __launch_bounds__(256) void k_kproj(const unsigned short* __restrict__ kT,
                                               const unsigned short* __restrict__ Wkbf,
                                               const float* __restrict__ bk,
                                               unsigned short* __restrict__ kp) {
    int b = blockIdx.y;
    int hwblk = blockIdx.x * 64;
    int t = threadIdx.x;
    int w = t >> 6, lane = t & 63;
    int n = lane & 15;        // hw col within wave tile / o row within A tile
    int kg = lane >> 4;       // k-group
    int hw = hwblk + w * 16 + n;

    f32x4_t acc[16];
#pragma unroll
    for (int m = 0; m < 16; ++m) acc[m] = f32x4_t{0.f, 0.f, 0.f, 0.f};

    const unsigned short* kTrow = kT + ((size_t)b * HWN + hw) * 256 + kg * 8;
    const unsigned short* wbase = Wkbf + (size_t)n * 256 + kg * 8;

#pragma unroll 2
    for (int ks = 0; ks < 8; ++ks) {
        bf16x8_t bfrag = *reinterpret_cast<const bf16x8_t*>(kTrow + ks * 32);
#pragma unroll
        for (int m = 0; m < 16; ++m) {
            bf16x8_t afrag = *reinterpret_cast<const bf16x8_t*>(wbase + (size_t)m * 16 * 256 + ks * 32);
            acc[m] = __builtin_amdgcn_mfma_f32_16x16x32_bf16(afrag, bfrag, acc[m], 0, 0, 0);
        }
    }

    // epilogue: bias + bf16, transpose via LDS, coalesced writeout
    __shared__ unsigned short tile[256 * 72];
    int col = w * 16 + n;
#pragma unroll
    for (int m = 0; m < 16; ++m) {
#pragma unroll
        for (int r = 0; r < 4; ++r) {
            int o = m * 16 + kg * 4 + r;
            tile[o * 72 + col] = bf16bits(acc[m][r] + bk[o]);
        }
    }
    __syncthreads();
    const size_t outbase = (size_t)b * 256 * HWN + hwblk;
#pragma unroll
    for (int p = 0; p < 4; ++p) {
        int o = p * 64 + (t >> 2);
        int c0 = (t & 3) * 16;
        uint4 v0 = *(uint4*)&tile[o * 72 + c0];
        uint4 v1 = *(uint4*)&tile[o * 72 + c0 + 8];
        *(uint4*)(kp + outbase + (size_t)o * HWN + c0)     = v0;
        *(uint4*)(kp + outbase + (size_t)o * HWN + c0 + 8) = v1;
    }
}

// ---------------- K3: sum-pass — scores -> exp -> per-(b,q) tile partials -----
__global__ __launch_bounds__(256) void k_sums(const float* __restrict__ qp,
                                              const unsigned short* __restrict__ kp,
                                              const int* __restrict__ mask,
                                              float* __restrict__ partial) {
    int hwt = blockIdx.x, qt = blockIdx.y, b = blockIdx.z;
    int t = threadIdx.x;
    int hw = hwt * 256 + t;
    int mv = mask[b * HWN + hw];
    int qbase = b * QQ + qt * QT;
    const float* qpb = qp + (size_t)qbase * 256;
    float sums[QT] = {};
#pragma unroll 1
    for (int n = 0; n < NH; ++n) {
        float kv[32];
        const unsigned short* kpp = kp + ((size_t)(b * 256 + n * 32)) * HWN + hw;
#pragma unroll
        for (int c = 0; c < 32; ++c) kv[c] = bf16tof(kpp[(size_t)c * HWN]);
#pragma unroll
        for (int qq = 0; qq < QT; ++qq) {
            const float* qr = qpb + qq * 256 + n * 32;
            float s0 = 0.f, s1 = 0.f, s2 = 0.f, s3 = 0.f;
#pragma unroll
            for (int c = 0; c < 32; c += 4) {
                s0 = fmaf(qr[c + 0], kv[c + 0], s0);
                s1 = fmaf(qr[c + 1], kv[c + 1], s1);
                s2 = fmaf(qr[c + 2], kv[c + 2], s2);
                s3 = fmaf(qr[c + 3], kv[c + 3], s3);
            }
            float e = __expf((s0 + s1) + (s2 + s3));
            sums[qq] += mv ? 0.0f : e;
        }
    }
    __shared__ float red[QT][4];
#pragma unroll
    for (int qq = 0; qq < QT; ++qq) {
        float v = sums[qq];
#pragma unroll
        for (int off = 32; off; off >>= 1) v += __shfl_xor(v, off, 64);
        if ((t & 63) == 0) red[qq][t >> 6] = v;
    }
    __syncthreads();
    if (t < QT) {
        float s = red[t][0] + red[t][1] + red[t][2] + red[t][3];
        partial[(size_t)(qbase + t) * NT + hwt] = s;
    }
}

// ---------------- K4: inv_sum[b,q] ---------------------------------------------
__global__ void k_invsum(const float* __restrict__ partial, float* __restrict__ inv) {
    int i = blockIdx.x * 256 + threadIdx.x;
    if (i < BB * QQ) {
        float s = 0.0f;
#pragma unroll
        for (int j = 0; j < NT; ++j) s += partial[(size_t)i * NT + j];
        inv[i] = 1.0f / s;
    }
}

// ---------------- K5: write-pass — recompute scores, write normalized ---------
__global__ __launch_bounds__(256) void k_write(const float* __restrict__ qp,
                                               const unsigned short* __restrict__ kp,
                                               const int* __restrict__ mask,
                                               const float* __restrict__ inv,
                                               float* __restrict__ out) {
    int hwt = blockIdx.x, qt = blockIdx.y, b = blockIdx.z;
    int t = threadIdx.x;
    int hw = hwt * 256 + t;
    int mv = mask[b * HWN + hw];
    int qbase = b * QQ + qt * QT;
    const float* qpb = qp + (size_t)qbase * 256;
    float invq[QT];
#pragma unroll
    for (int qq = 0; qq < QT; ++qq) invq[qq] = inv[qbase + qq];
#pragma unroll 1
    for (int n = 0; n < NH; ++n) {
        float kv[32];
        const unsigned short* kpp = kp + ((size_t)(b * 256 + n * 32)) * HWN + hw;
#pragma unroll
        for (int c = 0; c < 32; ++c) kv[c] = bf16tof(kpp[(size_t)c * HWN]);
#pragma unroll
        for (int qq = 0; qq < QT; ++qq) {
            const float* qr = qpb + qq * 256 + n * 32;
            float s0 = 0.f, s1 = 0.f, s2 = 0.f, s3 = 0.f;
#pragma unroll
            for (int c = 0; c < 32; c += 4) {
                s0 = fmaf(qr[c + 0], kv[c + 0], s0);
                s1 = fmaf(qr[c + 1], kv[c + 1], s1);
                s2 = fmaf(qr[c + 2], kv[c + 2], s2);
                s3 = fmaf(qr[c + 3], kv[c + 3], s3);
            }
            float e = __expf((s0 + s1) + (s2 + s3)) * invq[qq];
            out[(((size_t)(qbase + qq)) * NH + n) * HWN + hw] = mv ? 0.0f : e;
        }
    }
}

extern "C" void kernel_launch(void* const* d_in, const int* in_sizes, int n_in,
                              void* d_out, int out_size, void* d_ws, size_t ws_size,
                              hipStream_t stream) {
    const float* q    = (const float*)d_in[0];
    const float* k    = (const float*)d_in[1];
    const float* Wq   = (const float*)d_in[2];
    const float* bq   = (const float*)d_in[3];
    const float* Wk   = (const float*)d_in[4];
    const float* bk   = (const float*)d_in[5];
    const int*   mask = (const int*)d_in[6];
    float* out = (float*)d_out;

    char* base = (char*)d_ws;
    unsigned short* kT   = (unsigned short*)(base);              // 33,554,432 B
    unsigned short* kp   = (unsigned short*)(base + 33554432);   // 33,554,432 B
    float*  qp      = (float*)(base + 67108864);                 // 1,638,400 B
    float*  WqT     = (float*)(base + 68747264);                 //   262,144 B
    unsigned short* Wkbf = (unsigned short*)(base + 69009408);   //   131,072 B
    float*  partial = (float*)(base + 69140480);                 //   102,400 B
    float*  inv     = (float*)(base + 69242880);                 //     6,400 B
    if (ws_size < (size_t)69249280) return;

    k_prep  <<<dim3(512), dim3(256), 0, stream>>>(Wq, Wk, WqT, Wkbf);
    k_qproj <<<dim3(400), dim3(256), 0, stream>>>(q, WqT, bq, qp);
    k_tconv <<<dim3(64, 4, 16), dim3(256), 0, stream>>>(k, kT);
    k_kproj <<<dim3(64, 16), dim3(256), 0, stream>>>(kT, Wkbf, bk, kp);
    k_sums  <<<dim3(NT, QQ / QT, 16), dim3(256), 0, stream>>>(qp, kp, mask, partial);
    k_invsum<<<dim3(7), dim3(256), 0, stream>>>(partial, inv);
    k_write <<<dim3(NT, QQ / QT, 16), dim3(256), 0, stream>>>(qp, kp, mask, inv, out);
}

// Round 4
// 216.568 us; speedup vs baseline: 1.7659x; 1.4569x over previous
//
#include <hip/hip_runtime.h>
#include <hip/hip_bf16.h>
#include <math.h>

// Problem constants
#define BB 16
#define QQ 100
#define NH 8
#define HD 32
#define HWN 4096
#define NORM_FACT 0.17677669529663687f   // 32^-0.5
#define QPAD 128        // q rows padded to 128 (4 tiles of 32)
#define NSLOT 64        // partial-sum slots per q row (16 hw strips x 4 waves)

typedef short bf16x8_t __attribute__((ext_vector_type(8)));
typedef float f32x4_t  __attribute__((ext_vector_type(4)));

__device__ __forceinline__ unsigned short bf16bits(float f) {
    __hip_bfloat16 h = __float2bfloat16(f);           // RNE
    return __builtin_bit_cast(unsigned short, h);
}
__device__ __forceinline__ float bf16tof(unsigned short u) {
    union { unsigned int i; float f; } x; x.i = (unsigned int)u << 16; return x.f;
}

// ---------------- K0: WqT (fp32 transpose) + Wk -> bf16 (no transpose) --------
__global__ void k_prep(const float* __restrict__ Wq, const float* __restrict__ Wk,
                       float* __restrict__ WqT, unsigned short* __restrict__ Wkbf) {
    int idx = blockIdx.x;
    int h = threadIdx.x;
    if (idx < 256) {
        WqT[idx * 256 + h] = Wq[h * 256 + idx];
    } else {
        int r = idx - 256;
        Wkbf[r * 256 + h] = bf16bits(Wk[r * 256 + h]);
    }
}

// ---------------- K1: q-proj -> bf16 hi/lo split, padded to 128 rows ----------
__global__ __launch_bounds__(256) void k_qproj(const float* __restrict__ q,
                                               const float* __restrict__ WqT,
                                               const float* __restrict__ bq,
                                               unsigned short* __restrict__ qphi,
                                               unsigned short* __restrict__ qplo) {
    int blk = blockIdx.x;             // 16 b x 32 qtiles
    int b = blk >> 5, q0 = (blk & 31) * 4;
    int h = threadIdx.x;
    size_t obase = ((size_t)b * QPAD + q0) * 256 + h;
    if (q0 >= QQ) {                   // padding rows -> zeros
#pragma unroll
        for (int i = 0; i < 4; ++i) { qphi[obase + i * 256] = 0; qplo[obase + i * 256] = 0; }
        return;
    }
    __shared__ float qsh[4][256];
    int ibase = (b * QQ + q0) * 256;
#pragma unroll
    for (int i = 0; i < 4; ++i) qsh[i][h] = q[ibase + i * 256 + h];
    __syncthreads();
    float bias = bq[h];
    float a0 = bias, a1 = bias, a2 = bias, a3 = bias;
    for (int c = 0; c < 256; ++c) {
        float wv = WqT[c * 256 + h];
        a0 = fmaf(qsh[0][c], wv, a0);
        a1 = fmaf(qsh[1][c], wv, a1);
        a2 = fmaf(qsh[2][c], wv, a2);
        a3 = fmaf(qsh[3][c], wv, a3);
    }
    float a[4] = {a0 * NORM_FACT, a1 * NORM_FACT, a2 * NORM_FACT, a3 * NORM_FACT};
#pragma unroll
    for (int i = 0; i < 4; ++i) {
        unsigned short hi = bf16bits(a[i]);
        qphi[obase + i * 256] = hi;
        qplo[obase + i * 256] = bf16bits(a[i] - bf16tof(hi));
    }
}

// ---------------- K2a: kT[b][hw][c] bf16 <- k[b][c][hw] fp32 (LDS transpose) --
__global__ __launch_bounds__(256) void k_tconv(const float* __restrict__ k,
                                               unsigned short* __restrict__ kT) {
    int b = blockIdx.z, c0 = blockIdx.y * 64, hw0 = blockIdx.x * 64;
    int t = threadIdx.x;
    __shared__ float lds[64][65];
    const float* src = k + ((size_t)b * 256 + c0) * HWN + hw0;
    int col = t & 63, r0 = t >> 6;
#pragma unroll
    for (int i = 0; i < 16; ++i) {
        int r = i * 4 + r0;
        lds[r][col] = src[(size_t)r * HWN + col];
    }
    __syncthreads();
    int hw = t >> 2, cc = (t & 3) * 16;
    unsigned short* dst = kT + ((size_t)b * HWN + hw0 + hw) * 256 + c0 + cc;
    uint4 v0, v1;
    unsigned int* w0 = (unsigned int*)&v0;
    unsigned int* w1 = (unsigned int*)&v1;
#pragma unroll
    for (int j = 0; j < 4; ++j) {
        w0[j] = (unsigned int)bf16bits(lds[cc + 2*j + 0][hw])
              | ((unsigned int)bf16bits(lds[cc + 2*j + 1][hw]) << 16);
        w1[j] = (unsigned int)bf16bits(lds[cc + 8 + 2*j + 0][hw])
              | ((unsigned int)bf16bits(lds[cc + 8 + 2*j + 1][hw]) << 16);
    }
    *(uint4*)(dst)     = v0;
    *(uint4*)(dst + 8) = v1;
}

// ---------------- K2b: kpT[b][hw][o] bf16 = (Wk . k + bk)^T via MFMA ----------
// block = 4 waves; wave computes o=0..255 x 16 hw; block covers 64 hw
__global__ __launch_bounds__(256) void k_kproj(const unsigned short* __restrict__ kT,
                                               const unsigned short* __restrict__ Wkbf,
                                               const float* __restrict__ bk,
                                               unsigned short* __restrict__ kpT) {
    int b = blockIdx.y;
    int hwblk = blockIdx.x * 64;
    int t = threadIdx.x;
    int w = t >> 6, lane = t & 63;
    int n15 = lane & 15;      // hw col within wave tile / o row within A tile
    int kg = lane >> 4;       // k-group
    int hw = hwblk + w * 16 + n15;

    f32x4_t acc[16];
#pragma unroll
    for (int m = 0; m < 16; ++m) acc[m] = f32x4_t{0.f, 0.f, 0.f, 0.f};

    const unsigned short* kTrow = kT + ((size_t)b * HWN + hw) * 256 + kg * 8;
    const unsigned short* wbase = Wkbf + (size_t)n15 * 256 + kg * 8;

#pragma unroll 2
    for (int ks = 0; ks < 8; ++ks) {
        bf16x8_t bfrag = *reinterpret_cast<const bf16x8_t*>(kTrow + ks * 32);
#pragma unroll
        for (int m = 0; m < 16; ++m) {
            bf16x8_t afrag = *reinterpret_cast<const bf16x8_t*>(wbase + (size_t)m * 16 * 256 + ks * 32);
            acc[m] = __builtin_amdgcn_mfma_f32_16x16x32_bf16(afrag, bfrag, acc[m], 0, 0, 0);
        }
    }

    // epilogue: bias + bf16, transpose via LDS -> kpT[b][hw][o]
    __shared__ unsigned short tile2[64 * 264];     // 264 = 256 + 8 pad (bank spread)
    int hw_l = w * 16 + n15;
#pragma unroll
    for (int m = 0; m < 16; ++m) {
        ushort4 pk;
        unsigned short* pkp = (unsigned short*)&pk;
#pragma unroll
        for (int r = 0; r < 4; ++r) {
            int o = m * 16 + kg * 4 + r;
            pkp[r] = bf16bits(acc[m][r] + bk[o]);
        }
        *(ushort4*)&tile2[hw_l * 264 + m * 16 + kg * 4] = pk;
    }
    __syncthreads();
    int hw_r = t >> 2, sub = t & 3;
    unsigned short* dst = kpT + ((size_t)b * HWN + hwblk + hw_r) * 256;
#pragma unroll
    for (int j = 0; j < 8; ++j) {
        int o = j * 32 + sub * 8;
        uint4 v = *(uint4*)&tile2[hw_r * 264 + o];
        *(uint4*)(dst + o) = v;
    }
}

// ---------------- K3: sum-pass via MFMA ----------------------------------------
// grid (16 hw strips of 256, 4 q tiles of 32, 16 b); 4 waves; wave = 64-hw substrip
__global__ __launch_bounds__(256) void k_sums(const unsigned short* __restrict__ qphi,
                                              const unsigned short* __restrict__ qplo,
                                              const unsigned short* __restrict__ kpT,
                                              const int* __restrict__ mask,
                                              float* __restrict__ partial) {
    int hws = blockIdx.x, qt = blockIdx.y, b = blockIdx.z;
    int t = threadIdx.x, w = t >> 6, lane = t & 63;
    int n15 = lane & 15, kg = lane >> 4;
    int hw0 = hws * 256 + w * 64;
    float mm[4];
#pragma unroll
    for (int ht = 0; ht < 4; ++ht)
        mm[ht] = mask[b * HWN + hw0 + ht * 16 + n15] ? 0.0f : 1.0f;
    const unsigned short* ahi_b = qphi + ((size_t)(b * QPAD + qt * 32 + n15)) * 256 + kg * 8;
    const unsigned short* alo_b = qplo + ((size_t)(b * QPAD + qt * 32 + n15)) * 256 + kg * 8;
    const unsigned short* brow  = kpT  + ((size_t)(b * HWN + hw0 + n15)) * 256 + kg * 8;
    float sums[2][4] = {};
#pragma unroll 1
    for (int n = 0; n < NH; ++n) {
        bf16x8_t bf[4];
#pragma unroll
        for (int ht = 0; ht < 4; ++ht)
            bf[ht] = *reinterpret_cast<const bf16x8_t*>(brow + (size_t)(ht * 16) * 256 + n * 32);
#pragma unroll
        for (int mt = 0; mt < 2; ++mt) {
            bf16x8_t ahi = *reinterpret_cast<const bf16x8_t*>(ahi_b + (size_t)(mt * 16) * 256 + n * 32);
            bf16x8_t alo = *reinterpret_cast<const bf16x8_t*>(alo_b + (size_t)(mt * 16) * 256 + n * 32);
#pragma unroll
            for (int ht = 0; ht < 4; ++ht) {
                f32x4_t acc = {0.f, 0.f, 0.f, 0.f};
                acc = __builtin_amdgcn_mfma_f32_16x16x32_bf16(ahi, bf[ht], acc, 0, 0, 0);
                acc = __builtin_amdgcn_mfma_f32_16x16x32_bf16(alo, bf[ht], acc, 0, 0, 0);
#pragma unroll
                for (int r = 0; r < 4; ++r)
                    sums[mt][r] += __expf(acc[r]) * mm[ht];
            }
        }
    }
#pragma unroll
    for (int mt = 0; mt < 2; ++mt)
#pragma unroll
        for (int r = 0; r < 4; ++r) {
            float v = sums[mt][r];
            v += __shfl_xor(v, 1, 64);
            v += __shfl_xor(v, 2, 64);
            v += __shfl_xor(v, 4, 64);
            v += __shfl_xor(v, 8, 64);
            if (n15 == 0) {
                int qrow = qt * 32 + mt * 16 + kg * 4 + r;
                partial[((size_t)b * QPAD + qrow) * NSLOT + hws * 4 + w] = v;
            }
        }
}

// ---------------- K4: inv_sum[b,q] ---------------------------------------------
__global__ void k_invsum(const float* __restrict__ partial, float* __restrict__ inv) {
    int i = blockIdx.x * 256 + threadIdx.x;
    if (i < BB * QQ) {
        int b = i / QQ, qq = i % QQ;
        const float* p = partial + ((size_t)b * QPAD + qq) * NSLOT;
        float s = 0.0f;
#pragma unroll
        for (int j = 0; j < NSLOT; ++j) s += p[j];
        inv[i] = 1.0f / s;
    }
}

// ---------------- K5: write-pass via MFMA — normalized output ------------------
__global__ __launch_bounds__(256) void k_write(const unsigned short* __restrict__ qphi,
                                               const unsigned short* __restrict__ qplo,
                                               const unsigned short* __restrict__ kpT,
                                               const int* __restrict__ mask,
                                               const float* __restrict__ inv,
                                               float* __restrict__ out) {
    int hws = blockIdx.x, qt = blockIdx.y, b = blockIdx.z;
    int t = threadIdx.x, w = t >> 6, lane = t & 63;
    int n15 = lane & 15, kg = lane >> 4;
    int hw0 = hws * 256 + w * 64;
    float mm[4];
#pragma unroll
    for (int ht = 0; ht < 4; ++ht)
        mm[ht] = mask[b * HWN + hw0 + ht * 16 + n15] ? 0.0f : 1.0f;
    float invq[2][4];
#pragma unroll
    for (int mt = 0; mt < 2; ++mt)
#pragma unroll
        for (int r = 0; r < 4; ++r) {
            int qrow = qt * 32 + mt * 16 + kg * 4 + r;
            invq[mt][r] = (qrow < QQ) ? inv[b * QQ + qrow] : 0.0f;
        }
    const unsigned short* ahi_b = qphi + ((size_t)(b * QPAD + qt * 32 + n15)) * 256 + kg * 8;
    const unsigned short* alo_b = qplo + ((size_t)(b * QPAD + qt * 32 + n15)) * 256 + kg * 8;
    const unsigned short* brow  = kpT  + ((size_t)(b * HWN + hw0 + n15)) * 256 + kg * 8;
    __shared__ float lt[4][16][65];   // per-wave 16q x 64hw staging tile
#pragma unroll 1
    for (int n = 0; n < NH; ++n) {
        bf16x8_t bf[4];
#pragma unroll
        for (int ht = 0; ht < 4; ++ht)
            bf[ht] = *reinterpret_cast<const bf16x8_t*>(brow + (size_t)(ht * 16) * 256 + n * 32);
#pragma unroll 1
        for (int mt = 0; mt < 2; ++mt) {
            bf16x8_t ahi = *reinterpret_cast<const bf16x8_t*>(ahi_b + (size_t)(mt * 16) * 256 + n * 32);
            bf16x8_t alo = *reinterpret_cast<const bf16x8_t*>(alo_b + (size_t)(mt * 16) * 256 + n * 32);
#pragma unroll
            for (int ht = 0; ht < 4; ++ht) {
                f32x4_t acc = {0.f, 0.f, 0.f, 0.f};
                acc = __builtin_amdgcn_mfma_f32_16x16x32_bf16(ahi, bf[ht], acc, 0, 0, 0);
                acc = __builtin_amdgcn_mfma_f32_16x16x32_bf16(alo, bf[ht], acc, 0, 0, 0);
#pragma unroll
                for (int r = 0; r < 4; ++r)
                    lt[w][kg * 4 + r][ht * 16 + n15] = __expf(acc[r]) * mm[ht] * invq[mt][r];
            }
            __syncthreads();
#pragma unroll
            for (int rr = 0; rr < 16; ++rr) {
                int qrow = qt * 32 + mt * 16 + rr;
                if (qrow < QQ)
                    out[(((size_t)(b * QQ + qrow)) * NH + n) * HWN + hw0 + lane] = lt[w][rr][lane];
            }
            __syncthreads();
        }
    }
}

extern "C" void kernel_launch(void* const* d_in, const int* in_sizes, int n_in,
                              void* d_out, int out_size, void* d_ws, size_t ws_size,
                              hipStream_t stream) {
    const float* q    = (const float*)d_in[0];
    const float* k    = (const float*)d_in[1];
    const float* Wq   = (const float*)d_in[2];
    const float* bq   = (const float*)d_in[3];
    const float* Wk   = (const float*)d_in[4];
    const float* bk   = (const float*)d_in[5];
    const int*   mask = (const int*)d_in[6];
    float* out = (float*)d_out;

    char* base = (char*)d_ws;
    unsigned short* kT   = (unsigned short*)(base);              // 33,554,432 B
    unsigned short* kpT  = (unsigned short*)(base + 33554432);   // 33,554,432 B
    unsigned short* qphi = (unsigned short*)(base + 67108864);   //  1,048,576 B
    unsigned short* qplo = (unsigned short*)(base + 68157440);   //  1,048,576 B
    float*  WqT     = (float*)(base + 69206016);                 //    262,144 B
    unsigned short* Wkbf = (unsigned short*)(base + 69468160);   //    131,072 B
    float*  partial = (float*)(base + 69599232);                 //    524,288 B
    float*  inv     = (float*)(base + 70123520);                 //      6,400 B
    if (ws_size < (size_t)70129920) return;

    k_prep  <<<dim3(512), dim3(256), 0, stream>>>(Wq, Wk, WqT, Wkbf);
    k_qproj <<<dim3(512), dim3(256), 0, stream>>>(q, WqT, bq, qphi, qplo);
    k_tconv <<<dim3(64, 4, 16), dim3(256), 0, stream>>>(k, kT);
    k_kproj <<<dim3(64, 16), dim3(256), 0, stream>>>(kT, Wkbf, bk, kpT);
    k_sums  <<<dim3(16, 4, 16), dim3(256), 0, stream>>>(qphi, qplo, kpT, mask, partial);
    k_invsum<<<dim3(7), dim3(256), 0, stream>>>(partial, inv);
    k_write <<<dim3(16, 4, 16), dim3(256), 0, stream>>>(qphi, qplo, kpT, mask, inv, out);
}